// Round 1
// baseline (386.203 us; speedup 1.0000x reference)
//
#include <hip/hip_runtime.h>
#include <cstdint>

#define BB 64
#define SS 2048
#define HH 512

// ---------------------------------------------------------------------------
// Kernel 1: per-row syntax scan. One block per batch row (64 blocks).
// Computes nesting (Lindley recursion via (sum, min-prefix) segmented scan)
// and segments (cumsum % 8), packs idx = nest*8 + seg.
// ---------------------------------------------------------------------------
__global__ __launch_bounds__(256) void scan_kernel(const int* __restrict__ tok,
                                                   int* __restrict__ idx) {
    const int b = blockIdx.x;
    const int tid = threadIdx.x;
    const int* t = tok + (size_t)b * SS;

    // 8 contiguous tokens per thread (two int4 loads)
    int4 w0 = reinterpret_cast<const int4*>(t)[tid * 2 + 0];
    int4 w1 = reinterpret_cast<const int4*>(t)[tid * 2 + 1];
    int tk[8] = {w0.x, w0.y, w0.z, w0.w, w1.x, w1.y, w1.z, w1.w};

    int ls[8], lmin[8], lseg[8];
    int s = 0, m = 2147483647, sg = 0;
#pragma unroll
    for (int j = 0; j < 8; ++j) {
        int v = tk[j];
        int open_ = (v == 40) | (v == 123) | (v == 91);
        int close_ = (v == 41) | (v == 125) | (v == 93);
        s += open_ - close_;
        m = min(m, s);
        sg += (v > 39990) ? 1 : 0;
        ls[j] = s; lmin[j] = m; lseg[j] = sg;
    }

    // Block-wide inclusive scan over per-thread aggregates.
    // Combine (left ⊕ right): S = Sl+Sr ; M = min(Ml, Sl+Mr) ; G = Gl+Gr
    __shared__ int sS[256], sM[256], sG[256];
    sS[tid] = s; sM[tid] = m; sG[tid] = sg;
    __syncthreads();
    for (int off = 1; off < 256; off <<= 1) {
        int aS = 0, aM = 2147483647, aG = 0;
        bool has = (tid >= off);
        if (has) { aS = sS[tid - off]; aM = sM[tid - off]; aG = sG[tid - off]; }
        __syncthreads();
        if (has) {
            sM[tid] = min(aM, aS + sM[tid]);
            sS[tid] = aS + sS[tid];
            sG[tid] = aG + sG[tid];
        }
        __syncthreads();
    }
    int pS = 0, pM = 2147483647, pG = 0;
    if (tid > 0) { pS = sS[tid - 1]; pM = sM[tid - 1]; pG = sG[tid - 1]; }

    int res[8];
#pragma unroll
    for (int j = 0; j < 8; ++j) {
        int gs = pS + ls[j];                    // inclusive cumsum
        int rm = min(pM, pS + lmin[j]);         // inclusive running min
        int nest = gs - min(rm, 0);             // Lindley level
        nest = max(0, min(15, nest));
        int seg = (pG + lseg[j]) & 7;
        res[j] = nest * 8 + seg;
    }
    int4* op = reinterpret_cast<int4*>(idx + (size_t)b * SS + tid * 8);
    op[0] = make_int4(res[0], res[1], res[2], res[3]);
    op[1] = make_int4(res[4], res[5], res[6], res[7]);
}

// ---------------------------------------------------------------------------
// Kernel 2: f32 GEMM  C[M,512] = A[M,512] @ Wm[512,512]
// 64x64 tile, 256 threads, 4x4 micro-tile, K-tile 16 staged in LDS.
// Handles M < 64 via guards (used for nest/seg tables too).
// ---------------------------------------------------------------------------
__global__ __launch_bounds__(256) void gemm_kernel(const float* __restrict__ A,
                                                   const float* __restrict__ Wm,
                                                   float* __restrict__ C, int M) {
    __shared__ float As[16][64];   // [k][m]
    __shared__ float Bs[16][64];   // [k][n]
    const int bm = blockIdx.x * 64;
    const int bn = blockIdx.y * 64;
    const int tid = threadIdx.x;
    const int tx = tid & 15;       // n direction
    const int ty = tid >> 4;       // m direction

    float acc[4][4];
#pragma unroll
    for (int i = 0; i < 4; ++i)
#pragma unroll
        for (int j = 0; j < 4; ++j) acc[i][j] = 0.0f;

    for (int k0 = 0; k0 < 512; k0 += 16) {
        // A tile: 64 m x 16 k, one float4 per thread
        {
            int mm = tid >> 2;
            int kq = (tid & 3) << 2;
            float4 av = make_float4(0.f, 0.f, 0.f, 0.f);
            int gm = bm + mm;
            if (gm < M)
                av = *reinterpret_cast<const float4*>(A + (size_t)gm * 512 + k0 + kq);
            As[kq + 0][mm] = av.x; As[kq + 1][mm] = av.y;
            As[kq + 2][mm] = av.z; As[kq + 3][mm] = av.w;
        }
        // B tile: 16 k x 64 n, one float4 per thread
        {
            int kk = tid >> 4;
            int nn = (tid & 15) << 2;
            float4 bv = *reinterpret_cast<const float4*>(
                Wm + (size_t)(k0 + kk) * 512 + bn + nn);
            *reinterpret_cast<float4*>(&Bs[kk][nn]) = bv;
        }
        __syncthreads();
#pragma unroll
        for (int kk = 0; kk < 16; ++kk) {
            float4 a = *reinterpret_cast<const float4*>(&As[kk][ty << 2]);
            float4 b = *reinterpret_cast<const float4*>(&Bs[kk][tx << 2]);
            float av_[4] = {a.x, a.y, a.z, a.w};
            float bv_[4] = {b.x, b.y, b.z, b.w};
#pragma unroll
            for (int i = 0; i < 4; ++i)
#pragma unroll
                for (int j = 0; j < 4; ++j) acc[i][j] += av_[i] * bv_[j];
        }
        __syncthreads();
    }
#pragma unroll
    for (int i = 0; i < 4; ++i) {
        int row = bm + (ty << 2) + i;
        if (row < M) {
            float4 o = make_float4(acc[i][0], acc[i][1], acc[i][2], acc[i][3]);
            *reinterpret_cast<float4*>(C + (size_t)row * 512 + bn + (tx << 2)) = o;
        }
    }
}

// ---------------------------------------------------------------------------
// Kernel 3: out[b,s,:] = P[s,:] + N[nest,:] + G[seg,:]   (write-bound)
// Block = 256 threads = 2 batch rows x 128 float4 columns, s-major grid so
// consecutive blocks share the same P row (L1/L2 hot).
// ---------------------------------------------------------------------------
__global__ __launch_bounds__(256) void out_kernel(const float4* __restrict__ P,
                                                  const float4* __restrict__ N,
                                                  const float4* __restrict__ G,
                                                  const int* __restrict__ idx,
                                                  float4* __restrict__ out) {
    const int blk = blockIdx.x;           // 0 .. S*32-1
    const int s = blk >> 5;
    const int bp = blk & 31;
    const int ty = threadIdx.x >> 7;      // 0..1
    const int tx = threadIdx.x & 127;     // float4 column
    const int b = bp * 2 + ty;
    const size_t r = (size_t)b * SS + s;

    const int id = idx[r];
    const int n = id >> 3;
    const int g = id & 7;

    float4 p = P[(size_t)s * 128 + tx];
    float4 nv = N[(size_t)n * 128 + tx];
    float4 gv = G[(size_t)g * 128 + tx];
    float4 o;
    o.x = p.x + nv.x + gv.x;
    o.y = p.y + nv.y + gv.y;
    o.z = p.z + nv.z + gv.z;
    o.w = p.w + nv.w + gv.w;
    out[r * 128 + tx] = o;
}

// ---------------------------------------------------------------------------
extern "C" void kernel_launch(void* const* d_in, const int* in_sizes, int n_in,
                              void* d_out, int out_size, void* d_ws, size_t ws_size,
                              hipStream_t stream) {
    const int* tok = (const int*)d_in[0];      // [64,2048] int32
    const float* pos = (const float*)d_in[1];  // [2048,512]
    const float* nest = (const float*)d_in[2]; // [16,512]
    const float* seg = (const float*)d_in[3];  // [8,512]
    const float* W = (const float*)d_in[4];    // [1536,512]
    float* out = (float*)d_out;                // [64,2048,512]

    char* ws = (char*)d_ws;
    int* idx = (int*)ws;                                    // 512 KB
    float* P = (float*)(ws + 524288);                       // 4 MB
    float* N = (float*)(ws + 524288 + 4194304);             // 32 KB
    float* G = (float*)(ws + 524288 + 4194304 + 32768);     // 16 KB

    scan_kernel<<<BB, 256, 0, stream>>>(tok, idx);
    gemm_kernel<<<dim3(32, 8), 256, 0, stream>>>(pos, W, P, 2048);
    gemm_kernel<<<dim3(1, 8), 256, 0, stream>>>(nest, W + 512 * 512, N, 16);
    gemm_kernel<<<dim3(1, 8), 256, 0, stream>>>(seg, W + 1024 * 512, G, 8);
    out_kernel<<<SS * 32, 256, 0, stream>>>(
        (const float4*)P, (const float4*)N, (const float4*)G, idx, (float4*)out);
}

// Round 2
// 310.774 us; speedup vs baseline: 1.2427x; 1.2427x over previous
//
#include <hip/hip_runtime.h>
#include <cstdint>

#define BB 64
#define SS 2048

// ---------------------------------------------------------------------------
// Fused prep kernel, 368 blocks x 256 threads:
//   blocks [0,256)   : P = pos @ W[0:512]     (2048x512 f32 GEMM, 64x64 tiles,
//                      register-prefetch double-buffered LDS staging)
//   blocks [256,304) : NG[24][512] = {nest @ W[512:1024] ; seg @ W[1024:1536]}
//                      (trivial dot kernel, 1 output/thread)
//   blocks [304,368) : per-row syntax scan -> idx = nest*8 + seg
// ---------------------------------------------------------------------------
__global__ __launch_bounds__(256) void prep_kernel(
    const int* __restrict__ tok, const float* __restrict__ pos,
    const float* __restrict__ nest, const float* __restrict__ seg,
    const float* __restrict__ W,
    int* __restrict__ idx, float* __restrict__ P, float* __restrict__ NG) {
    const int blk = blockIdx.x;
    const int tid = threadIdx.x;

    if (blk < 256) {
        // ---- P GEMM: 64x64 tile, 4x4 micro, K-tile 16 ----
        __shared__ float As[16][68];   // [k][m], pad 68: staging writes 2-way,
                                       // row stride 272B = 16-aligned for b128 reads
        __shared__ float Bs[16][64];   // [k][n]
        const int bm = (blk >> 3) << 6;     // 32 m-tiles
        const int bn = (blk & 7) << 6;      // 8 n-tiles
        const int am = tid >> 2, ak = (tid & 3) << 2;   // A staging coords
        const int bk = tid >> 4, bn2 = (tid & 15) << 2; // B staging coords
        const int tn = tid & 15, tm = tid >> 4;         // micro-tile coords

        const float* Ap = pos + (size_t)(bm + am) * 512 + ak;
        const float* Bp = W + (size_t)bk * 512 + bn + bn2;
        float4 aR = *(const float4*)Ap;
        float4 bR = *(const float4*)Bp;

        float acc[4][4];
#pragma unroll
        for (int i = 0; i < 4; ++i)
#pragma unroll
            for (int j = 0; j < 4; ++j) acc[i][j] = 0.0f;

        for (int k0 = 0; k0 < 512; k0 += 16) {
            __syncthreads();
            As[ak + 0][am] = aR.x; As[ak + 1][am] = aR.y;
            As[ak + 2][am] = aR.z; As[ak + 3][am] = aR.w;
            *(float4*)&Bs[bk][bn2] = bR;
            __syncthreads();
            if (k0 + 16 < 512) {   // prefetch next tile; overlaps compute below
                aR = *(const float4*)(Ap + k0 + 16);
                bR = *(const float4*)(Bp + (size_t)(k0 + 16) * 512);
            }
#pragma unroll
            for (int kk = 0; kk < 16; ++kk) {
                float4 a = *(const float4*)&As[kk][tm << 2];
                float4 b = *(const float4*)&Bs[kk][tn << 2];
                float av[4] = {a.x, a.y, a.z, a.w};
                float bv[4] = {b.x, b.y, b.z, b.w};
#pragma unroll
                for (int i = 0; i < 4; ++i)
#pragma unroll
                    for (int j = 0; j < 4; ++j) acc[i][j] += av[i] * bv[j];
            }
        }
#pragma unroll
        for (int i = 0; i < 4; ++i) {
            float4 o = make_float4(acc[i][0], acc[i][1], acc[i][2], acc[i][3]);
            *(float4*)(P + (size_t)(bm + (tm << 2) + i) * 512 + bn + (tn << 2)) = o;
        }
    } else if (blk < 304) {
        // ---- NG dot kernel: rows 0..15 = nest@W1, rows 16..23 = seg@W2 ----
        const int b2 = blk - 256;
        const int row = b2 >> 1;
        const int col = ((b2 & 1) << 8) + tid;
        const float* Ta = (row < 16) ? (nest + (size_t)row * 512)
                                     : (seg + (size_t)(row - 16) * 512);
        const float* Wx = W + ((row < 16) ? (size_t)512 * 512 : (size_t)1024 * 512);
        float s = 0.0f;
#pragma unroll 8
        for (int k = 0; k < 512; ++k) s += Ta[k] * Wx[(size_t)k * 512 + col];
        NG[(size_t)row * 512 + col] = s;
    } else {
        // ---- syntax scan: one block per batch row ----
        __shared__ int sS[256], sM[256], sG[256];
        const int b = blk - 304;
        const int* t = tok + (size_t)b * SS;
        int4 w0 = reinterpret_cast<const int4*>(t)[tid * 2 + 0];
        int4 w1 = reinterpret_cast<const int4*>(t)[tid * 2 + 1];
        int tk[8] = {w0.x, w0.y, w0.z, w0.w, w1.x, w1.y, w1.z, w1.w};

        int ls[8], lmin[8], lseg[8];
        int s = 0, m = 2147483647, sg = 0;
#pragma unroll
        for (int j = 0; j < 8; ++j) {
            int v = tk[j];
            int open_ = (v == 40) | (v == 123) | (v == 91);
            int close_ = (v == 41) | (v == 125) | (v == 93);
            s += open_ - close_;
            m = min(m, s);
            sg += (v > 39990) ? 1 : 0;
            ls[j] = s; lmin[j] = m; lseg[j] = sg;
        }
        sS[tid] = s; sM[tid] = m; sG[tid] = sg;
        __syncthreads();
        for (int off = 1; off < 256; off <<= 1) {
            int aS = 0, aM = 2147483647, aG = 0;
            bool has = (tid >= off);
            if (has) { aS = sS[tid - off]; aM = sM[tid - off]; aG = sG[tid - off]; }
            __syncthreads();
            if (has) {
                sM[tid] = min(aM, aS + sM[tid]);
                sS[tid] = aS + sS[tid];
                sG[tid] = aG + sG[tid];
            }
            __syncthreads();
        }
        int pS = 0, pM = 2147483647, pG = 0;
        if (tid > 0) { pS = sS[tid - 1]; pM = sM[tid - 1]; pG = sG[tid - 1]; }

        int res[8];
#pragma unroll
        for (int j = 0; j < 8; ++j) {
            int gs = pS + ls[j];
            int rm = min(pM, pS + lmin[j]);
            int nst = gs - min(rm, 0);
            nst = max(0, min(15, nst));
            int sgm = (pG + lseg[j]) & 7;
            res[j] = nst * 8 + sgm;
        }
        int4* op = reinterpret_cast<int4*>(idx + (size_t)b * SS + tid * 8);
        op[0] = make_int4(res[0], res[1], res[2], res[3]);
        op[1] = make_int4(res[4], res[5], res[6], res[7]);
    }
}

// ---------------------------------------------------------------------------
// Output kernel: out[b,s,:] = P[s,:] + NG[nest,:] + NG[16+seg,:]
// Block = (s, group of 8 b): 256 threads = 2 b-rows x 128 float4 cols,
// loop 4x over b. P row loaded ONCE per thread, reused 8x per block.
// s-major grid so consecutive blocks share the P row in L2.
// ---------------------------------------------------------------------------
__global__ __launch_bounds__(256) void out_kernel(const float4* __restrict__ P,
                                                  const float4* __restrict__ NG,
                                                  const int* __restrict__ idx,
                                                  float4* __restrict__ out) {
    const int s = blockIdx.x >> 3;
    const int bg = blockIdx.x & 7;
    const int tx = threadIdx.x & 127;
    const int tz = threadIdx.x >> 7;

    const float4 p = P[(size_t)s * 128 + tx];
#pragma unroll
    for (int i = 0; i < 4; ++i) {
        const int b = (bg << 3) + (i << 1) + tz;
        const size_t r = (size_t)b * SS + s;
        const int id = idx[r];
        const float4 nv = NG[(size_t)(id >> 3) * 128 + tx];
        const float4 gv = NG[(size_t)(16 + (id & 7)) * 128 + tx];
        float4 o;
        o.x = p.x + nv.x + gv.x;
        o.y = p.y + nv.y + gv.y;
        o.z = p.z + nv.z + gv.z;
        o.w = p.w + nv.w + gv.w;
        out[r * 128 + tx] = o;
    }
}

// ---------------------------------------------------------------------------
extern "C" void kernel_launch(void* const* d_in, const int* in_sizes, int n_in,
                              void* d_out, int out_size, void* d_ws, size_t ws_size,
                              hipStream_t stream) {
    const int* tok = (const int*)d_in[0];      // [64,2048] int32
    const float* pos = (const float*)d_in[1];  // [2048,512]
    const float* nest = (const float*)d_in[2]; // [16,512]
    const float* seg = (const float*)d_in[3];  // [8,512]
    const float* W = (const float*)d_in[4];    // [1536,512]
    float* out = (float*)d_out;                // [64,2048,512]

    char* ws = (char*)d_ws;
    int* idx = (int*)ws;                               // 512 KB
    float* P = (float*)(ws + (512 << 10));             // 4 MB
    float* NG = (float*)(ws + (512 << 10) + (4 << 20)); // 48 KB

    prep_kernel<<<368, 256, 0, stream>>>(tok, pos, nest, seg, W, idx, P, NG);
    out_kernel<<<SS * 8, 256, 0, stream>>>(
        (const float4*)P, (const float4*)NG, idx, (float4*)out);
}